// Round 6
// baseline (152.924 us; speedup 1.0000x reference)
//
#include <hip/hip_runtime.h>
#include <hip/hip_bf16.h>

#define B_ 256
#define L_ 1225   // placeholder guard (unused)
#undef L_
#define L_ 225
#define D_ 1280
#define H_ 256
#define U_ 256
#define LT 45     // real rows per block-tile (5 * 45 = 225 exact)
#define LTP 48    // padded rows computed (3 MFMA row-frags)

typedef __bf16  bf16x8 __attribute__((ext_vector_type(8)));
typedef float   f32x4  __attribute__((ext_vector_type(4)));
typedef unsigned short u16x8 __attribute__((ext_vector_type(8)));

__device__ __forceinline__ unsigned short f2bf(float f) {
    union { __hip_bfloat16 h; unsigned short u; } cv;
    cv.h = __float2bfloat16(f);   // RNE
    return cv.u;
}

__device__ __forceinline__ void gload_lds16(const void* g, void* l) {
    __builtin_amdgcn_global_load_lds(
        (const __attribute__((address_space(1))) unsigned int*)g,
        (__attribute__((address_space(3))) unsigned int*)l,
        16, 0, 0);
}

__device__ __forceinline__ float wredsum(float x) {
#pragma unroll
    for (int off = 32; off > 0; off >>= 1) x += __shfl_xor(x, off, 64);
    return x;
}

// ---------------- kernel 1: W1 [D][U] f32 -> W1t [U][D] bf16 ----------------
__global__ void k_prep_w1t(const float* __restrict__ W1, __hip_bfloat16* __restrict__ w1t) {
    int idx = blockIdx.x * 256 + threadIdx.x;   // idx = k*U_+u
    int k = idx / U_;
    int u = idx % U_;
    w1t[(size_t)u * D_ + k] = __float2bfloat16(W1[idx]);
}

// ------------- kernel 2: ph[b][u] = hidden[b].W2[:,u] + b1[u] + b2[u] -------
__global__ void k_proj_h(const float* __restrict__ hidden, const float* __restrict__ W2,
                         const float* __restrict__ b1, const float* __restrict__ b2,
                         float* __restrict__ ph) {
    __shared__ float sh[H_];
    int b = blockIdx.x;
    int u = threadIdx.x;
    sh[u] = hidden[b * H_ + u];
    __syncthreads();
    float acc = b1[u] + b2[u];
#pragma unroll 8
    for (int h = 0; h < H_; ++h) acc += sh[h] * W2[h * U_ + u];
    ph[b * U_ + u] = acc;
}

// ---------------- kernel 3: L-tiled fused kernel, 2 blocks/CU ---------------
// 1280 blocks (b = blk/5, tile s5 = blk%5) x 512 threads (8 waves).
// GEMM 48x256x1280 K-streamed (A dbuf 2x6KB reg-staged, B dbuf 2x32KB via
// global_load_lds) -> tanh*V -> exp weights (no-max) -> context re-reads the
// block's 230KB of features (L2/L3-warm: gap is only the remaining K-loop).
// LDS (79552 B total -> 2 blocks/CU):
//   A0 @0 (6144) | A1 @6144 | B0 @12288 (32768) | B1 @45056 | sL @77824
//   (8*48*4=1536) | sW @79360 (192)
__global__ __launch_bounds__(512, 4) void k_fused(
        const float* __restrict__ feat,
        const __hip_bfloat16* __restrict__ w1t,
        const float* __restrict__ ph,
        const float* __restrict__ Vv,
        float* __restrict__ num,
        float* __restrict__ den) {
    __shared__ __align__(128) char smem[79552];
    float* sL = (float*)(smem + 77824);
    float* sW = (float*)(smem + 79360);

    const int tid  = threadIdx.x;
    const int lane = tid & 63;
    const int wave = tid >> 6;     // 0..7 = column-wave
    const int blk  = blockIdx.x;
    const int b    = blk / 5;
    const int s5   = blk - b * 5;
    const int l0   = s5 * LT;

    const float* featB = feat + ((size_t)b * L_ + l0) * D_;

    // ---- A staging map: threads 0..383, one 8-f32 chunk each ----
    const int ar   = tid >> 3;                   // 0..63 (rows used: 0..47)
    const int arc  = ar < LT ? ar : (LT - 1);    // clamp pad rows
    const int ac8  = tid & 7;                    // 8-f32 chunk within 64-col row
    const bool aAct = (tid < 384);
    const float* aSrc0 = featB + (size_t)arc * D_ + ac8 * 8;
    const int aOff = ar * 128 + ((ac8 * 16) ^ ((ar & 7) << 4));

    // ---- B staging map: 4 chunks/thread, linear LDS dest, inv-swz source ---
    const __hip_bfloat16* bSrc[4];
    int bDst[4];
#pragma unroll
    for (int pass = 0; pass < 4; ++pass) {
        int sI  = pass * 512 + tid;       // 0..2047
        int u   = sI >> 3;
        int c8s = sI & 7;
        int c8g = c8s ^ (u & 7);
        bSrc[pass] = w1t + (size_t)u * D_ + c8g * 8;
        bDst[pass] = sI * 16;
    }

    f32x4 acc[3][2];
#pragma unroll
    for (int mi = 0; mi < 3; ++mi)
#pragma unroll
        for (int ni = 0; ni < 2; ++ni)
            acc[mi][ni] = (f32x4){0.f, 0.f, 0.f, 0.f};

    const int u0 = wave * 32 + (lane & 15);

    auto loadA = [&](int kt, f32x4* v) {
        if (aAct) {
            const float* src = aSrc0 + kt * 64;
            v[0] = *reinterpret_cast<const f32x4*>(src);
            v[1] = *reinterpret_cast<const f32x4*>(src + 4);
        }
    };
    auto storeA = [&](const f32x4* v, char* bufA) {
        if (aAct) {
            u16x8 w;
            w[0] = f2bf(v[0][0]); w[1] = f2bf(v[0][1]); w[2] = f2bf(v[0][2]); w[3] = f2bf(v[0][3]);
            w[4] = f2bf(v[1][0]); w[5] = f2bf(v[1][1]); w[6] = f2bf(v[1][2]); w[7] = f2bf(v[1][3]);
            *reinterpret_cast<u16x8*>(bufA + aOff) = w;
        }
    };
    auto stageB = [&](int kt, char* bufB) {
#pragma unroll
        for (int pass = 0; pass < 4; ++pass)
            gload_lds16(bSrc[pass] + kt * 64, bufB + bDst[pass]);
    };
    auto compute = [&](const char* bufA, const char* bufB) {
#pragma unroll
        for (int ks = 0; ks < 2; ++ks) {
            const int kk2 = (ks * 32 + ((lane >> 4) << 3)) * 2;
            bf16x8 a[3], bb[2];
#pragma unroll
            for (int mi = 0; mi < 3; ++mi) {
                int r = mi * 16 + (lane & 15);
                a[mi] = *reinterpret_cast<const bf16x8*>(
                    bufA + r * 128 + (kk2 ^ ((r & 7) << 4)));
            }
            bb[0] = *reinterpret_cast<const bf16x8*>(
                bufB + u0 * 128 + (kk2 ^ ((u0 & 7) << 4)));
            bb[1] = *reinterpret_cast<const bf16x8*>(
                bufB + (u0 + 16) * 128 + (kk2 ^ (((u0 + 16) & 7) << 4)));
#pragma unroll
            for (int mi = 0; mi < 3; ++mi)
#pragma unroll
                for (int ni = 0; ni < 2; ++ni)
                    acc[mi][ni] = __builtin_amdgcn_mfma_f32_16x16x32_bf16(
                        a[mi], bb[ni], acc[mi][ni], 0, 0, 0);
        }
    };

    // ---- K-loop: 20 steps of 64, both operands double-buffered (T14) ----
    {
        f32x4 v[2];
        loadA(0, v);
        stageB(0, smem + 12288);
        storeA(v, smem);
    }
    __syncthreads();
    int cur = 0;
    for (int kt = 0; kt < 20; ++kt) {
        f32x4 v[2];
        if (kt < 19) {
            loadA(kt + 1, v);                       // issue early (T14)
            stageB(kt + 1, smem + 12288 + (cur ^ 1) * 32768);
        }
        compute(smem + cur * 6144, smem + 12288 + cur * 32768);
        if (kt < 19) storeA(v, smem + (cur ^ 1) * 6144);
        __syncthreads();
        cur ^= 1;
    }

    // ---- epilogue: tanh(acc+ph)*V -> per-wave partial logits ----
    const float* phB = ph + b * 256;
    float ph0 = phB[u0], ph1 = phB[u0 + 16];
    float v0  = Vv[u0],  v1  = Vv[u0 + 16];
#pragma unroll
    for (int mi = 0; mi < 3; ++mi) {
#pragma unroll
        for (int rg = 0; rg < 4; ++rg) {
            int row = mi * 16 + ((lane >> 4) << 2) + rg;   // 0..47
            float x0 = acc[mi][0][rg] + ph0;
            float x1 = acc[mi][1][rg] + ph1;
            float sl = (1.f - 2.f / (__expf(2.f * x0) + 1.f)) * v0
                     + (1.f - 2.f / (__expf(2.f * x1) + 1.f)) * v1;
            sl += __shfl_xor(sl, 1, 64);
            sl += __shfl_xor(sl, 2, 64);
            sl += __shfl_xor(sl, 4, 64);
            sl += __shfl_xor(sl, 8, 64);
            if ((lane & 15) == 0) sL[wave * LTP + row] = sl;
        }
    }
    __syncthreads();

    // ---- weights w = exp(logit) (no max: |logit| <= sum|V| ~ 13) ----
    if (wave == 0) {
        float w = 0.f;
        if (lane < LT) {
            float lg = 0.f;
#pragma unroll
            for (int wc = 0; wc < 8; ++wc) lg += sL[wc * LTP + lane];
            w = __expf(lg);
            sW[lane] = w;
        }
        float d = wredsum(w);
        if (lane == 0) den[blk] = d;
    }
    __syncthreads();

    // ---- context partial: re-read features (L2/L3-warm), weighted sum ----
    f32x4 c[5];
#pragma unroll
    for (int ch = 0; ch < 5; ++ch) c[ch] = (f32x4){0.f, 0.f, 0.f, 0.f};
    for (int l = wave; l < LT; l += 8) {
        float wgt = sW[l];
        const float* fr = featB + (size_t)l * D_ + (lane << 2);
#pragma unroll
        for (int ch = 0; ch < 5; ++ch)
            c[ch] += wgt * *reinterpret_cast<const f32x4*>(fr + ch * 256);
    }
    __syncthreads();   // sL/sW reads done; LDS free for reduction

    // ---- reduce 8 wave partials -> num[blk] ----
    float* pc = (float*)smem;   // [8][1280] f32 = 40KB, reuses A/B region
#pragma unroll
    for (int ch = 0; ch < 5; ++ch)
        *reinterpret_cast<f32x4*>(pc + wave * 1280 + ch * 256 + (lane << 2)) = c[ch];
    __syncthreads();
    if (tid < 320) {
        f32x4 s = (f32x4){0.f, 0.f, 0.f, 0.f};
#pragma unroll
        for (int w = 0; w < 8; ++w)
            s += *reinterpret_cast<const f32x4*>(pc + w * 1280 + (tid << 2));
        *reinterpret_cast<f32x4*>(num + (size_t)blk * 1280 + (tid << 2)) = s;
    }
}

// ---------------- kernel 4: combine 5 tile-partials per batch ----------------
__global__ void k_combine(const float* __restrict__ num, const float* __restrict__ den,
                          float* __restrict__ out) {
    int b = blockIdx.x;
    int t = threadIdx.x;   // 0..319
    f32x4 n = (f32x4){0.f, 0.f, 0.f, 0.f};
    float d = 0.f;
#pragma unroll
    for (int s = 0; s < 5; ++s) {
        n += *reinterpret_cast<const f32x4*>(num + (size_t)(b * 5 + s) * 1280 + (t << 2));
        d += den[b * 5 + s];
    }
    n *= (1.f / d);
    *reinterpret_cast<f32x4*>(out + (size_t)b * D_ + (t << 2)) = n;
}

extern "C" void kernel_launch(void* const* d_in, const int* in_sizes, int n_in,
                              void* d_out, int out_size, void* d_ws, size_t ws_size,
                              hipStream_t stream) {
    const float* feat   = (const float*)d_in[0];
    const float* hidden = (const float*)d_in[1];
    const float* W1     = (const float*)d_in[2];
    const float* b1     = (const float*)d_in[3];
    const float* W2     = (const float*)d_in[4];
    const float* b2     = (const float*)d_in[5];
    const float* Vv     = (const float*)d_in[6];
    // bV (d_in[7]) is a uniform logit shift -> softmax-invariant; skipped.

    char* ws = (char*)d_ws;
    __hip_bfloat16* w1t = (__hip_bfloat16*)(ws);    // 655360 B
    float* ph  = (float*)(ws + 655360);             // 262144 B
    float* num = (float*)(ws + 917504);             // 1280*1280*4 = 6553600 B
    float* den = (float*)(ws + 7471104);            // 5120 B
    float* out = (float*)d_out;

    k_prep_w1t<<<(U_ * D_) / 256, 256, 0, stream>>>(W1, w1t);
    k_proj_h  <<<B_, U_, 0, stream>>>(hidden, W2, b1, b2, ph);
    k_fused   <<<B_ * 5, 512, 0, stream>>>(feat, w1t, ph, Vv, num, den);
    k_combine <<<B_, 320, 0, stream>>>(num, den, out);
}